// Round 1
// 765.969 us; speedup vs baseline: 1.0847x; 1.0847x over previous
//
#include <hip/hip_runtime.h>
#include <hip/hip_bf16.h>
#include <math.h>

// Problem constants
#define BB 2
#define LL 512
#define CC 256
#define HH 8
#define DD 32
#define LN_EPS 1e-5f
#define SCALE 0.17677669529663687f   // 1/sqrt(32)
#define RSQRT2 0.70710678118654752f

// ---------------------------------------------------------------------------
// K1: qkv = x @ w_qkv^T, scattered into q/v as [B,H,L,D] and k TRANSPOSED as
// [B,H,D,L] so K3's QK inner loop reads K coalesced over j.
// M=1024 rows (b,l), N=768 cols, K=256. 64x64 tile, 4x4 micro-tile.
// ---------------------------------------------------------------------------
__global__ __launch_bounds__(256) void k1_qkv(const float* __restrict__ x,
                                              const float* __restrict__ w,
                                              float* __restrict__ qkv_out) {
    __shared__ float xs[16][64];
    __shared__ float wsd[16][64];
    const int row0 = blockIdx.x * 64;
    const int col0 = blockIdx.y * 64;
    const int t  = threadIdx.x;
    const int ry = t >> 4;   // 0..15
    const int cx = t & 15;   // 0..15
    const int lr = t >> 2;   // 0..63 row for staging load
    const int lq = t & 3;    // 0..3  16B chunk
    float acc[4][4] = {};
    for (int k0 = 0; k0 < 256; k0 += 16) {
        float4 xv = *(const float4*)(x + (row0 + lr) * 256 + k0 + 4 * lq);
        float4 wv = *(const float4*)(w + (col0 + lr) * 256 + k0 + 4 * lq);
        xs[4*lq+0][lr] = xv.x; xs[4*lq+1][lr] = xv.y;
        xs[4*lq+2][lr] = xv.z; xs[4*lq+3][lr] = xv.w;
        wsd[4*lq+0][lr] = wv.x; wsd[4*lq+1][lr] = wv.y;
        wsd[4*lq+2][lr] = wv.z; wsd[4*lq+3][lr] = wv.w;
        __syncthreads();
#pragma unroll
        for (int kk = 0; kk < 16; ++kk) {
            float4 a  = *(const float4*)&xs[kk][4*ry];
            float4 bb = *(const float4*)&wsd[kk][4*cx];
            float av[4] = {a.x, a.y, a.z, a.w};
            float bv[4] = {bb.x, bb.y, bb.z, bb.w};
#pragma unroll
            for (int rr = 0; rr < 4; ++rr)
#pragma unroll
                for (int cc = 0; cc < 4; ++cc)
                    acc[rr][cc] = fmaf(av[rr], bv[cc], acc[rr][cc]);
        }
        __syncthreads();
    }
#pragma unroll
    for (int rr = 0; rr < 4; ++rr) {
        const int row = row0 + 4*ry + rr;
        const int b = row >> 9, l = row & 511;
#pragma unroll
        for (int cc = 0; cc < 4; ++cc) {
            const int o = col0 + 4*cx + cc;
            const int three = o >> 8;      // uniform per block (64-col tiles)
            const int hh = (o >> 5) & 7;
            const int dd = o & 31;
            int idx;
            if (three == 1)   // k -> transposed [b,h,d,l]
                idx = 262144 + ((b*8 + hh)*32 + dd)*512 + l;
            else              // q, v -> [b,h,l,d]
                idx = three * 262144 + ((b*8 + hh)*512 + l)*32 + dd;
            qkv_out[idx] = acc[rr][cc];
        }
    }
}

// ---------------------------------------------------------------------------
// K2 (v2): rel_t[b,h,i,j] = LN_h( gelu( rp[b,i,j,:] . w_rel[h,:] + b_rel[h] ) )
// No LDS staging of rp: each rp element is read from global EXACTLY ONCE,
// fully coalesced. w_rel chunk (8 heads x 8 floats) lives in registers.
// Lane layout per wave: jh = lane>>5 (2 j's per iter), chunk = lane&31
// (8-float c-chunk). Reduce: xor1,2,4 on 8 accs (24 shfl) -> per-lane head
// select (7 cndmask) -> xor8,16 (2 shfl). GELU once/lane, LN across octet.
// Output staged in tiny LDS tile then stored coalesced to [B,H,L,L].
// ---------------------------------------------------------------------------
__global__ __launch_bounds__(256) void k2_rel(const float* __restrict__ rp,
                                              const float* __restrict__ wr,
                                              const float* __restrict__ br,
                                              const float* __restrict__ gam_p,
                                              const float* __restrict__ bet_p,
                                              float* __restrict__ rel_t) {
    __shared__ float st[8][65];           // [h][j-local], pad 65 -> no conflicts
    const int t    = threadIdx.x;
    const int lane = t & 63;
    const int wid  = t >> 6;
    const int blk  = blockIdx.x;          // 8192 = b(2) * i(512) * jt(8)
    const int jt = blk & 7;
    const int i  = (blk >> 3) & 511;
    const int b  = blk >> 12;
    const int j0 = jt << 6;
    const int chunk = lane & 31;          // which 8-float c-chunk
    const int jh    = lane >> 5;          // which of the 2 j's this iter
    const int h     = lane & 7;           // head owned after reduce

    // per-lane w_rel chunk for all 8 heads (64 VGPRs)
    float wreg[8][8];
    {
        const float4* wr4 = (const float4*)wr;
#pragma unroll
        for (int hh = 0; hh < 8; ++hh) {
            float4 w0 = wr4[hh*64 + chunk*2];
            float4 w1 = wr4[hh*64 + chunk*2 + 1];
            wreg[hh][0]=w0.x; wreg[hh][1]=w0.y; wreg[hh][2]=w0.z; wreg[hh][3]=w0.w;
            wreg[hh][4]=w1.x; wreg[hh][5]=w1.y; wreg[hh][6]=w1.z; wreg[hh][7]=w1.w;
        }
    }
    const float brv = br[h], gmv = gam_p[h], btv = bet_p[h];

    const float* base = rp + ((long)(b*512 + i)*512 + (j0 + wid*16 + jh)) * 256
                           + chunk*8;
    float4 a0 = *(const float4*)(base);
    float4 a1 = *(const float4*)(base + 4);
#pragma unroll
    for (int it = 0; it < 8; ++it) {
        float4 n0 = a0, n1 = a1;
        if (it < 7) {                      // 1-deep prefetch of next j-pair
            const float* np = base + (2*(it+1))*256;
            n0 = *(const float4*)(np);
            n1 = *(const float4*)(np + 4);
        }
        float acc[8];
#pragma unroll
        for (int hh = 0; hh < 8; ++hh) {
            float s = 0.f;
            s = fmaf(a0.x, wreg[hh][0], s);
            s = fmaf(a0.y, wreg[hh][1], s);
            s = fmaf(a0.z, wreg[hh][2], s);
            s = fmaf(a0.w, wreg[hh][3], s);
            s = fmaf(a1.x, wreg[hh][4], s);
            s = fmaf(a1.y, wreg[hh][5], s);
            s = fmaf(a1.z, wreg[hh][6], s);
            s = fmaf(a1.w, wreg[hh][7], s);
            acc[hh] = s;
        }
        // stage A: reduce within chunk-octets (bits 0..2 of lane)
#pragma unroll
        for (int hh = 0; hh < 8; ++hh) acc[hh] += __shfl_xor(acc[hh], 1);
#pragma unroll
        for (int hh = 0; hh < 8; ++hh) acc[hh] += __shfl_xor(acc[hh], 2);
#pragma unroll
        for (int hh = 0; hh < 8; ++hh) acc[hh] += __shfl_xor(acc[hh], 4);
        // stage B: lane selects its head's group-partial (static cndmask tree)
        float v0 = (h & 1) ? acc[1] : acc[0];
        float v1 = (h & 1) ? acc[3] : acc[2];
        float v2 = (h & 1) ? acc[5] : acc[4];
        float v3 = (h & 1) ? acc[7] : acc[6];
        float u0 = (h & 2) ? v1 : v0;
        float u1 = (h & 2) ? v3 : v2;
        float tot = (h & 4) ? u1 : u0;
        // stage C: reduce over the 4 chunk-groups (bits 3,4 of lane)
        tot += __shfl_xor(tot, 8);
        tot += __shfl_xor(tot, 16);

        const float r = tot + brv;
        const float g = 0.5f * r * (1.0f + erff(r * RSQRT2));
        // LayerNorm across the 8 heads of this octet
        float sg = g, sg2 = g * g;
        sg += __shfl_xor(sg, 1); sg2 += __shfl_xor(sg2, 1);
        sg += __shfl_xor(sg, 2); sg2 += __shfl_xor(sg2, 2);
        sg += __shfl_xor(sg, 4); sg2 += __shfl_xor(sg2, 4);
        const float mu  = sg * 0.125f;
        const float var = fmaf(sg2, 0.125f, -mu * mu);
        const float o = fmaf((g - mu) * rsqrtf(var + LN_EPS), gmv, btv);
        if ((lane & 31) < 8)               // one replica per (j,h) writes
            st[h][wid*16 + 2*it + jh] = o;
        a0 = n0; a1 = n1;
    }
    __syncthreads();
    // coalesced transposed store: runs of 32 consecutive j per half-wave
    const int h2 = t >> 5, j2 = t & 31;
    const long orow = ((long)(b*8 + h2) * 512 + i) * 512 + j0;
    rel_t[orow + j2]      = st[h2][j2];
    rel_t[orow + j2 + 32] = st[h2][j2 + 32];
}

// ---------------------------------------------------------------------------
// K3: attention. One wave per (b,h,i) row. K is [B,H,D,L] (transposed by K1)
// so QK loads are coalesced dwordx4 over j; q broadcast from registers.
// Lane owns j-quad {4*lane..+3} and {256+4*lane..+3}.
// ---------------------------------------------------------------------------
__global__ __launch_bounds__(256) void k3_attn(const float* __restrict__ qg,
                                               const float* __restrict__ kt,
                                               const float* __restrict__ vg,
                                               const float* __restrict__ rel_t,
                                               float* __restrict__ outg) {
    __shared__ float p_lds[4][512];
    const int lane = threadIdx.x & 63;
    const int wid  = threadIdx.x >> 6;
    const int row  = blockIdx.x * 4 + wid;       // 0..8191
    const int b = row >> 12;
    const int h = (row >> 9) & 7;
    const int i = row & 511;
    const int bh = b*8 + h;

    const float* qp = qg + (bh*512 + i) * 32;
    float qs[32];
#pragma unroll
    for (int dd = 0; dd < 8; ++dd) {
        float4 q4 = *(const float4*)(qp + 4*dd);
        qs[4*dd+0]=q4.x; qs[4*dd+1]=q4.y; qs[4*dd+2]=q4.z; qs[4*dd+3]=q4.w;
    }
    const float4* kt4  = (const float4*)(kt + (long)bh * 32 * 512);
    const float4* rel4 = (const float4*)(rel_t + ((long)bh * 512 + i) * 512);

    float4 s0 = {0.f,0.f,0.f,0.f}, s1 = {0.f,0.f,0.f,0.f};
#pragma unroll
    for (int dd = 0; dd < 32; ++dd) {
        float4 ka = kt4[dd*128 + lane];          // j = 4*lane..+3, coalesced
        float4 kb = kt4[dd*128 + 64 + lane];     // j = 256+4*lane..+3
        const float qd = qs[dd];
        s0.x = fmaf(qd, ka.x, s0.x); s0.y = fmaf(qd, ka.y, s0.y);
        s0.z = fmaf(qd, ka.z, s0.z); s0.w = fmaf(qd, ka.w, s0.w);
        s1.x = fmaf(qd, kb.x, s1.x); s1.y = fmaf(qd, kb.y, s1.y);
        s1.z = fmaf(qd, kb.z, s1.z); s1.w = fmaf(qd, kb.w, s1.w);
    }
    float4 r0 = rel4[lane], r1 = rel4[64 + lane];
    s0.x = (s0.x + r0.x) * SCALE; s0.y = (s0.y + r0.y) * SCALE;
    s0.z = (s0.z + r0.z) * SCALE; s0.w = (s0.w + r0.w) * SCALE;
    s1.x = (s1.x + r1.x) * SCALE; s1.y = (s1.y + r1.y) * SCALE;
    s1.z = (s1.z + r1.z) * SCALE; s1.w = (s1.w + r1.w) * SCALE;
    // row max
    float m = fmaxf(fmaxf(fmaxf(s0.x, s0.y), fmaxf(s0.z, s0.w)),
                    fmaxf(fmaxf(s1.x, s1.y), fmaxf(s1.z, s1.w)));
    m = fmaxf(m, __shfl_xor(m, 1));
    m = fmaxf(m, __shfl_xor(m, 2));
    m = fmaxf(m, __shfl_xor(m, 4));
    m = fmaxf(m, __shfl_xor(m, 8));
    m = fmaxf(m, __shfl_xor(m, 16));
    m = fmaxf(m, __shfl_xor(m, 32));
    // exp + sum
    s0.x = __expf(s0.x - m); s0.y = __expf(s0.y - m);
    s0.z = __expf(s0.z - m); s0.w = __expf(s0.w - m);
    s1.x = __expf(s1.x - m); s1.y = __expf(s1.y - m);
    s1.z = __expf(s1.z - m); s1.w = __expf(s1.w - m);
    float sum = ((s0.x + s0.y) + (s0.z + s0.w)) + ((s1.x + s1.y) + (s1.z + s1.w));
    sum += __shfl_xor(sum, 1);
    sum += __shfl_xor(sum, 2);
    sum += __shfl_xor(sum, 4);
    sum += __shfl_xor(sum, 8);
    sum += __shfl_xor(sum, 16);
    sum += __shfl_xor(sum, 32);
    const float inv = 1.0f / sum;
    s0.x *= inv; s0.y *= inv; s0.z *= inv; s0.w *= inv;
    s1.x *= inv; s1.y *= inv; s1.z *= inv; s1.w *= inv;
    *(float4*)&p_lds[wid][4*lane]       = s0;
    *(float4*)&p_lds[wid][256 + 4*lane] = s1;
    __syncthreads();

    // PV: lane = (d = lane&31, half = lane>>5); 4 independent acc chains
    const int d = lane & 31;
    const int half = lane >> 5;
    const float* vp = vg + (long)(bh*512) * 32 + (half * 256) * 32 + d;
    const float* pw = &p_lds[wid][half * 256];
    float a0 = 0.f, a1 = 0.f, a2 = 0.f, a3 = 0.f;
#pragma unroll 4
    for (int jj = 0; jj < 256; jj += 4) {
        a0 = fmaf(pw[jj + 0], vp[(jj + 0) * 32], a0);
        a1 = fmaf(pw[jj + 1], vp[(jj + 1) * 32], a1);
        a2 = fmaf(pw[jj + 2], vp[(jj + 2) * 32], a2);
        a3 = fmaf(pw[jj + 3], vp[(jj + 3) * 32], a3);
    }
    float acc = (a0 + a1) + (a2 + a3);
    acc += __shfl_xor(acc, 32);
    if (lane < 32)
        outg[(b*512 + i) * 256 + h * 32 + d] = acc;
}

// ---------------------------------------------------------------------------
// K4: out = attn @ w_proj^T + b_proj.  M=1024, N=256, K=256.
// ---------------------------------------------------------------------------
__global__ __launch_bounds__(256) void k4_proj(const float* __restrict__ a_in,
                                               const float* __restrict__ w,
                                               const float* __restrict__ bp,
                                               float* __restrict__ outg) {
    __shared__ float xs[16][64];
    __shared__ float wsd[16][64];
    const int row0 = blockIdx.x * 64;
    const int col0 = blockIdx.y * 64;
    const int t  = threadIdx.x;
    const int ry = t >> 4;
    const int cx = t & 15;
    const int lr = t >> 2;
    const int lq = t & 3;
    float acc[4][4] = {};
    for (int k0 = 0; k0 < 256; k0 += 16) {
        float4 xv = *(const float4*)(a_in + (row0 + lr) * 256 + k0 + 4 * lq);
        float4 wv = *(const float4*)(w + (col0 + lr) * 256 + k0 + 4 * lq);
        xs[4*lq+0][lr] = xv.x; xs[4*lq+1][lr] = xv.y;
        xs[4*lq+2][lr] = xv.z; xs[4*lq+3][lr] = xv.w;
        wsd[4*lq+0][lr] = wv.x; wsd[4*lq+1][lr] = wv.y;
        wsd[4*lq+2][lr] = wv.z; wsd[4*lq+3][lr] = wv.w;
        __syncthreads();
#pragma unroll
        for (int kk = 0; kk < 16; ++kk) {
            float4 a  = *(const float4*)&xs[kk][4*ry];
            float4 bb = *(const float4*)&wsd[kk][4*cx];
            float av[4] = {a.x, a.y, a.z, a.w};
            float bv[4] = {bb.x, bb.y, bb.z, bb.w};
#pragma unroll
            for (int rr = 0; rr < 4; ++rr)
#pragma unroll
                for (int cc = 0; cc < 4; ++cc)
                    acc[rr][cc] = fmaf(av[rr], bv[cc], acc[rr][cc]);
        }
        __syncthreads();
    }
#pragma unroll
    for (int rr = 0; rr < 4; ++rr) {
        const int row = row0 + 4*ry + rr;
#pragma unroll
        for (int cc = 0; cc < 4; ++cc) {
            const int col = col0 + 4*cx + cc;
            outg[row * 256 + col] = acc[rr][cc] + bp[col];
        }
    }
}

// ---------------------------------------------------------------------------
extern "C" void kernel_launch(void* const* d_in, const int* in_sizes, int n_in,
                              void* d_out, int out_size, void* d_ws, size_t ws_size,
                              hipStream_t stream) {
    const float* x      = (const float*)d_in[0];
    const float* rp     = (const float*)d_in[1];
    const float* w_qkv  = (const float*)d_in[2];
    const float* w_rel  = (const float*)d_in[3];
    const float* b_rel  = (const float*)d_in[4];
    const float* gamma  = (const float*)d_in[5];
    const float* beta   = (const float*)d_in[6];
    const float* w_proj = (const float*)d_in[7];
    const float* b_proj = (const float*)d_in[8];
    float* out = (float*)d_out;
    float* ws  = (float*)d_ws;

    // workspace layout (floats):
    // q: [0, 262144)   k_t [B,H,D,L]: [262144, 524288)   v: [524288, 786432)
    // rel_t [B,H,L,L]: [786432, 4980736)     attn [B,L,C]: [4980736, 5242880)
    float* q     = ws;
    float* kk    = ws + 262144;
    float* vv    = ws + 524288;
    float* rel_t = ws + 786432;
    float* attn  = ws + 786432 + 4194304;

    k1_qkv<<<dim3(16, 12), 256, 0, stream>>>(x, w_qkv, q);
    k2_rel<<<8192, 256, 0, stream>>>(rp, w_rel, b_rel, gamma, beta, rel_t);
    k3_attn<<<2048, 256, 0, stream>>>(q, kk, vv, rel_t, attn);
    k4_proj<<<dim3(16, 4), 256, 0, stream>>>(attn, w_proj, b_proj, out);
}

// Round 2
// 762.257 us; speedup vs baseline: 1.0900x; 1.0049x over previous
//
#include <hip/hip_runtime.h>
#include <hip/hip_bf16.h>
#include <math.h>

// Problem constants
#define BB 2
#define LL 512
#define CC 256
#define HH 8
#define DD 32
#define LN_EPS 1e-5f
#define SCALE 0.17677669529663687f   // 1/sqrt(32)
#define RSQRT2 0.70710678118654752f

// ---------------------------------------------------------------------------
// K1: qkv = x @ w_qkv^T, scattered into q/v as [B,H,L,D] and k TRANSPOSED as
// [B,H,D,L] so the fused attention QK inner loop reads K coalesced over j.
// ---------------------------------------------------------------------------
__global__ __launch_bounds__(256) void k1_qkv(const float* __restrict__ x,
                                              const float* __restrict__ w,
                                              float* __restrict__ qkv_out) {
    __shared__ float xs[16][64];
    __shared__ float wsd[16][64];
    const int row0 = blockIdx.x * 64;
    const int col0 = blockIdx.y * 64;
    const int t  = threadIdx.x;
    const int ry = t >> 4;   // 0..15
    const int cx = t & 15;   // 0..15
    const int lr = t >> 2;   // 0..63 row for staging load
    const int lq = t & 3;    // 0..3  16B chunk
    float acc[4][4] = {};
    for (int k0 = 0; k0 < 256; k0 += 16) {
        float4 xv = *(const float4*)(x + (row0 + lr) * 256 + k0 + 4 * lq);
        float4 wv = *(const float4*)(w + (col0 + lr) * 256 + k0 + 4 * lq);
        xs[4*lq+0][lr] = xv.x; xs[4*lq+1][lr] = xv.y;
        xs[4*lq+2][lr] = xv.z; xs[4*lq+3][lr] = xv.w;
        wsd[4*lq+0][lr] = wv.x; wsd[4*lq+1][lr] = wv.y;
        wsd[4*lq+2][lr] = wv.z; wsd[4*lq+3][lr] = wv.w;
        __syncthreads();
#pragma unroll
        for (int kk = 0; kk < 16; ++kk) {
            float4 a  = *(const float4*)&xs[kk][4*ry];
            float4 bb = *(const float4*)&wsd[kk][4*cx];
            float av[4] = {a.x, a.y, a.z, a.w};
            float bv[4] = {bb.x, bb.y, bb.z, bb.w};
#pragma unroll
            for (int rr = 0; rr < 4; ++rr)
#pragma unroll
                for (int cc = 0; cc < 4; ++cc)
                    acc[rr][cc] = fmaf(av[rr], bv[cc], acc[rr][cc]);
        }
        __syncthreads();
    }
#pragma unroll
    for (int rr = 0; rr < 4; ++rr) {
        const int row = row0 + 4*ry + rr;
        const int b = row >> 9, l = row & 511;
#pragma unroll
        for (int cc = 0; cc < 4; ++cc) {
            const int o = col0 + 4*cx + cc;
            const int three = o >> 8;      // uniform per block (64-col tiles)
            const int hh = (o >> 5) & 7;
            const int dd = o & 31;
            int idx;
            if (three == 1)   // k -> transposed [b,h,d,l]
                idx = 262144 + ((b*8 + hh)*32 + dd)*512 + l;
            else              // q, v -> [b,h,l,d]
                idx = three * 262144 + ((b*8 + hh)*512 + l)*32 + dd;
            qkv_out[idx] = acc[rr][cc];
        }
    }
}

// ---------------------------------------------------------------------------
// K23 (fused rel + attention). One block per (b,i), 512 threads (8 waves).
//
// Phase 1 (rel): rel[h][j] = LN_h( gelu( rp[b,i,j,:] . w_rel[h,:] + b_rel[h] ) )
//   Wave w owns j in [64w, 64w+64), 2 j's per iter (jh = lane>>5), chunk =
//   lane&31 selects an 8-float c-slice; w_rel slice for all 8 heads in regs.
//   Reduce uses an interleaved butterfly/head-select: xor1 on 8 accs ->
//   select(h&1) -> xor2 on 4 -> select(h&2) -> xor4 on 2 -> select(h&4) ->
//   xor8,16.  16 swizzles vs 26 for the naive 3-stage version.
//   Result written to rel_lds[8][516] (pad 4 -> banks 4h+j, conflict-free,
//   rows stay 16B-aligned for float4 reads).
//
// Phase 2 (attention): one wave per head. QK over K^T [B,H,D,L] (coalesced
//   dwordx4), rel added from LDS, softmax in-wave, p overwrites rel row
//   in-place (wave-local), PV from V [B,H,L,D] (full-line dword loads).
//   rel never touches HBM.
// ---------------------------------------------------------------------------
__global__ __launch_bounds__(512) void k23_fused(const float* __restrict__ rp,
                                                 const float* __restrict__ wr,
                                                 const float* __restrict__ br,
                                                 const float* __restrict__ gam_p,
                                                 const float* __restrict__ bet_p,
                                                 const float* __restrict__ qg,
                                                 const float* __restrict__ kt,
                                                 const float* __restrict__ vg,
                                                 float* __restrict__ outg) {
    __shared__ float rel_lds[8 * 516];
    const int t    = threadIdx.x;
    const int lane = t & 63;
    const int wid  = t >> 6;              // 0..7
    const int b = blockIdx.x >> 9;
    const int i = blockIdx.x & 511;
    const int chunk = lane & 31;          // 8-float c-slice
    const int jh    = lane >> 5;          // which of 2 j's this iter
    const int h     = lane & 7;           // head owned after reduce

    // per-lane w_rel slice for all 8 heads (64 VGPRs)
    float wreg[8][8];
    {
        const float4* wr4 = (const float4*)wr;
#pragma unroll
        for (int hh = 0; hh < 8; ++hh) {
            float4 w0 = wr4[hh*64 + chunk*2];
            float4 w1 = wr4[hh*64 + chunk*2 + 1];
            wreg[hh][0]=w0.x; wreg[hh][1]=w0.y; wreg[hh][2]=w0.z; wreg[hh][3]=w0.w;
            wreg[hh][4]=w1.x; wreg[hh][5]=w1.y; wreg[hh][6]=w1.z; wreg[hh][7]=w1.w;
        }
    }
    const float brv = br[h], gmv = gam_p[h], btv = bet_p[h];

    const float* base = rp + ((long)(b*512 + i)*512 + (wid*64 + jh)) * 256
                           + chunk*8;
    float4 a0 = *(const float4*)(base);
    float4 a1 = *(const float4*)(base + 4);
#pragma unroll 2
    for (int it = 0; it < 32; ++it) {
        float4 n0 = a0, n1 = a1;
        if (it < 31) {                     // 1-deep prefetch of next j-pair
            const float* np = base + (2*(it+1))*256;
            n0 = *(const float4*)(np);
            n1 = *(const float4*)(np + 4);
        }
        float acc[8];
#pragma unroll
        for (int hh = 0; hh < 8; ++hh) {
            float s = 0.f;
            s = fmaf(a0.x, wreg[hh][0], s);
            s = fmaf(a0.y, wreg[hh][1], s);
            s = fmaf(a0.z, wreg[hh][2], s);
            s = fmaf(a0.w, wreg[hh][3], s);
            s = fmaf(a1.x, wreg[hh][4], s);
            s = fmaf(a1.y, wreg[hh][5], s);
            s = fmaf(a1.z, wreg[hh][6], s);
            s = fmaf(a1.w, wreg[hh][7], s);
            acc[hh] = s;
        }
        // interleaved butterfly + head-select: 16 swizzles total
#pragma unroll
        for (int hh = 0; hh < 8; ++hh) acc[hh] += __shfl_xor(acc[hh], 1);
        float v0 = (h & 1) ? acc[1] : acc[0];
        float v1 = (h & 1) ? acc[3] : acc[2];
        float v2 = (h & 1) ? acc[5] : acc[4];
        float v3 = (h & 1) ? acc[7] : acc[6];
        v0 += __shfl_xor(v0, 2); v1 += __shfl_xor(v1, 2);
        v2 += __shfl_xor(v2, 2); v3 += __shfl_xor(v3, 2);
        float u0 = (h & 2) ? v1 : v0;
        float u1 = (h & 2) ? v3 : v2;
        u0 += __shfl_xor(u0, 4); u1 += __shfl_xor(u1, 4);
        float tot = (h & 4) ? u1 : u0;
        tot += __shfl_xor(tot, 8);
        tot += __shfl_xor(tot, 16);

        const float r = tot + brv;
        const float g = 0.5f * r * (1.0f + erff(r * RSQRT2));
        // LayerNorm across the 8 heads of this octet
        float sg = g, sg2 = g * g;
        sg += __shfl_xor(sg, 1); sg2 += __shfl_xor(sg2, 1);
        sg += __shfl_xor(sg, 2); sg2 += __shfl_xor(sg2, 2);
        sg += __shfl_xor(sg, 4); sg2 += __shfl_xor(sg2, 4);
        const float mu  = sg * 0.125f;
        const float var = fmaf(sg2, 0.125f, -mu * mu);
        const float o = fmaf((g - mu) * rsqrtf(var + LN_EPS), gmv, btv);
        if ((lane & 31) < 8)               // one replica per (j,h) writes
            rel_lds[h * 516 + wid*64 + 2*it + jh] = o;
        a0 = n0; a1 = n1;
    }
    __syncthreads();

    // ---------------- Phase 2: attention, wave = head ----------------
    const int bh = b*8 + wid;
    const float* qp = qg + (bh*512 + i) * 32;
    float qs[32];
#pragma unroll
    for (int dd = 0; dd < 8; ++dd) {
        float4 q4 = *(const float4*)(qp + 4*dd);
        qs[4*dd+0]=q4.x; qs[4*dd+1]=q4.y; qs[4*dd+2]=q4.z; qs[4*dd+3]=q4.w;
    }
    const float4* kt4 = (const float4*)(kt + (long)bh * 32 * 512);
    float* relrow = &rel_lds[wid * 516];

    float4 s0 = {0.f,0.f,0.f,0.f}, s1 = {0.f,0.f,0.f,0.f};
#pragma unroll
    for (int dd = 0; dd < 32; ++dd) {
        float4 ka = kt4[dd*128 + lane];          // j = 4*lane..+3, coalesced
        float4 kb = kt4[dd*128 + 64 + lane];     // j = 256+4*lane..+3
        const float qd = qs[dd];
        s0.x = fmaf(qd, ka.x, s0.x); s0.y = fmaf(qd, ka.y, s0.y);
        s0.z = fmaf(qd, ka.z, s0.z); s0.w = fmaf(qd, ka.w, s0.w);
        s1.x = fmaf(qd, kb.x, s1.x); s1.y = fmaf(qd, kb.y, s1.y);
        s1.z = fmaf(qd, kb.z, s1.z); s1.w = fmaf(qd, kb.w, s1.w);
    }
    float4 r0 = *(const float4*)&relrow[4*lane];
    float4 r1 = *(const float4*)&relrow[256 + 4*lane];
    s0.x = (s0.x + r0.x) * SCALE; s0.y = (s0.y + r0.y) * SCALE;
    s0.z = (s0.z + r0.z) * SCALE; s0.w = (s0.w + r0.w) * SCALE;
    s1.x = (s1.x + r1.x) * SCALE; s1.y = (s1.y + r1.y) * SCALE;
    s1.z = (s1.z + r1.z) * SCALE; s1.w = (s1.w + r1.w) * SCALE;
    // row max
    float m = fmaxf(fmaxf(fmaxf(s0.x, s0.y), fmaxf(s0.z, s0.w)),
                    fmaxf(fmaxf(s1.x, s1.y), fmaxf(s1.z, s1.w)));
    m = fmaxf(m, __shfl_xor(m, 1));
    m = fmaxf(m, __shfl_xor(m, 2));
    m = fmaxf(m, __shfl_xor(m, 4));
    m = fmaxf(m, __shfl_xor(m, 8));
    m = fmaxf(m, __shfl_xor(m, 16));
    m = fmaxf(m, __shfl_xor(m, 32));
    // exp + sum
    s0.x = __expf(s0.x - m); s0.y = __expf(s0.y - m);
    s0.z = __expf(s0.z - m); s0.w = __expf(s0.w - m);
    s1.x = __expf(s1.x - m); s1.y = __expf(s1.y - m);
    s1.z = __expf(s1.z - m); s1.w = __expf(s1.w - m);
    float sum = ((s0.x + s0.y) + (s0.z + s0.w)) + ((s1.x + s1.y) + (s1.z + s1.w));
    sum += __shfl_xor(sum, 1);
    sum += __shfl_xor(sum, 2);
    sum += __shfl_xor(sum, 4);
    sum += __shfl_xor(sum, 8);
    sum += __shfl_xor(sum, 16);
    sum += __shfl_xor(sum, 32);
    const float inv = 1.0f / sum;
    s0.x *= inv; s0.y *= inv; s0.z *= inv; s0.w *= inv;
    s1.x *= inv; s1.y *= inv; s1.z *= inv; s1.w *= inv;
    // p overwrites rel row in place (wave-local, no barrier needed)
    *(float4*)&relrow[4*lane]       = s0;
    *(float4*)&relrow[256 + 4*lane] = s1;

    // PV: lane = (d = lane&31, half = lane>>5); 4 independent acc chains
    const int d = lane & 31;
    const int half = lane >> 5;
    const float* vp = vg + (long)bh * 512 * 32 + (half * 256) * 32 + d;
    const float* pw = relrow + half * 256;
    float a0s = 0.f, a1s = 0.f, a2s = 0.f, a3s = 0.f;
#pragma unroll 4
    for (int jj = 0; jj < 256; jj += 4) {
        a0s = fmaf(pw[jj + 0], vp[(jj + 0) * 32], a0s);
        a1s = fmaf(pw[jj + 1], vp[(jj + 1) * 32], a1s);
        a2s = fmaf(pw[jj + 2], vp[(jj + 2) * 32], a2s);
        a3s = fmaf(pw[jj + 3], vp[(jj + 3) * 32], a3s);
    }
    float acc = (a0s + a1s) + (a2s + a3s);
    acc += __shfl_xor(acc, 32);
    if (lane < 32)
        outg[(b*512 + i) * 256 + wid * 32 + d] = acc;
}

// ---------------------------------------------------------------------------
// K4: out = attn @ w_proj^T + b_proj.  M=1024, N=256, K=256.
// ---------------------------------------------------------------------------
__global__ __launch_bounds__(256) void k4_proj(const float* __restrict__ a_in,
                                               const float* __restrict__ w,
                                               const float* __restrict__ bp,
                                               float* __restrict__ outg) {
    __shared__ float xs[16][64];
    __shared__ float wsd[16][64];
    const int row0 = blockIdx.x * 64;
    const int col0 = blockIdx.y * 64;
    const int t  = threadIdx.x;
    const int ry = t >> 4;
    const int cx = t & 15;
    const int lr = t >> 2;
    const int lq = t & 3;
    float acc[4][4] = {};
    for (int k0 = 0; k0 < 256; k0 += 16) {
        float4 xv = *(const float4*)(a_in + (row0 + lr) * 256 + k0 + 4 * lq);
        float4 wv = *(const float4*)(w + (col0 + lr) * 256 + k0 + 4 * lq);
        xs[4*lq+0][lr] = xv.x; xs[4*lq+1][lr] = xv.y;
        xs[4*lq+2][lr] = xv.z; xs[4*lq+3][lr] = xv.w;
        wsd[4*lq+0][lr] = wv.x; wsd[4*lq+1][lr] = wv.y;
        wsd[4*lq+2][lr] = wv.z; wsd[4*lq+3][lr] = wv.w;
        __syncthreads();
#pragma unroll
        for (int kk = 0; kk < 16; ++kk) {
            float4 a  = *(const float4*)&xs[kk][4*ry];
            float4 bb = *(const float4*)&wsd[kk][4*cx];
            float av[4] = {a.x, a.y, a.z, a.w};
            float bv[4] = {bb.x, bb.y, bb.z, bb.w};
#pragma unroll
            for (int rr = 0; rr < 4; ++rr)
#pragma unroll
                for (int cc = 0; cc < 4; ++cc)
                    acc[rr][cc] = fmaf(av[rr], bv[cc], acc[rr][cc]);
        }
        __syncthreads();
    }
#pragma unroll
    for (int rr = 0; rr < 4; ++rr) {
        const int row = row0 + 4*ry + rr;
#pragma unroll
        for (int cc = 0; cc < 4; ++cc) {
            const int col = col0 + 4*cx + cc;
            outg[row * 256 + col] = acc[rr][cc] + bp[col];
        }
    }
}

// ---------------------------------------------------------------------------
extern "C" void kernel_launch(void* const* d_in, const int* in_sizes, int n_in,
                              void* d_out, int out_size, void* d_ws, size_t ws_size,
                              hipStream_t stream) {
    const float* x      = (const float*)d_in[0];
    const float* rp     = (const float*)d_in[1];
    const float* w_qkv  = (const float*)d_in[2];
    const float* w_rel  = (const float*)d_in[3];
    const float* b_rel  = (const float*)d_in[4];
    const float* gamma  = (const float*)d_in[5];
    const float* beta   = (const float*)d_in[6];
    const float* w_proj = (const float*)d_in[7];
    const float* b_proj = (const float*)d_in[8];
    float* out = (float*)d_out;
    float* ws  = (float*)d_ws;

    // workspace layout (floats):
    // q: [0, 262144)   k_t [B,H,D,L]: [262144, 524288)   v: [524288, 786432)
    // attn [B,L,C]: [786432, 1048576)   (rel never touches HBM any more)
    float* q    = ws;
    float* kk   = ws + 262144;
    float* vv   = ws + 524288;
    float* attn = ws + 786432;

    k1_qkv<<<dim3(16, 12), 256, 0, stream>>>(x, w_qkv, q);
    k23_fused<<<1024, 512, 0, stream>>>(rp, w_rel, b_rel, gamma, beta,
                                        q, kk, vv, attn);
    k4_proj<<<dim3(16, 4), 256, 0, stream>>>(attn, w_proj, b_proj, out);
}

// Round 3
// 752.651 us; speedup vs baseline: 1.1039x; 1.0128x over previous
//
#include <hip/hip_runtime.h>
#include <hip/hip_bf16.h>
#include <math.h>

// Problem constants
#define BB 2
#define LL 512
#define CC 256
#define HH 8
#define DD 32
#define LN_EPS 1e-5f
#define SCALE 0.17677669529663687f   // 1/sqrt(32)
#define RSQRT2 0.70710678118654752f

// DPP quad_perm cross-lane adds: same partner & add order as __shfl_xor(x,1/2)
// but issued on the VALU pipe (v_add_f32_dpp) instead of the DS pipe.
// quad_perm [1,0,3,2] = 0xB1 (xor1), [2,3,0,1] = 0x4E (xor2).
__device__ __forceinline__ float dpp_xor1(float x) {
    int r = __builtin_amdgcn_update_dpp(0, __float_as_int(x), 0xB1, 0xF, 0xF, true);
    return __int_as_float(r);
}
__device__ __forceinline__ float dpp_xor2(float x) {
    int r = __builtin_amdgcn_update_dpp(0, __float_as_int(x), 0x4E, 0xF, 0xF, true);
    return __int_as_float(r);
}

// ---------------------------------------------------------------------------
// K1: qkv = x @ w_qkv^T, scattered into q/v as [B,H,L,D] and k TRANSPOSED as
// [B,H,D,L] so the fused attention QK inner loop reads K coalesced over j.
// ---------------------------------------------------------------------------
__global__ __launch_bounds__(256) void k1_qkv(const float* __restrict__ x,
                                              const float* __restrict__ w,
                                              float* __restrict__ qkv_out) {
    __shared__ float xs[16][64];
    __shared__ float wsd[16][64];
    const int row0 = blockIdx.x * 64;
    const int col0 = blockIdx.y * 64;
    const int t  = threadIdx.x;
    const int ry = t >> 4;   // 0..15
    const int cx = t & 15;   // 0..15
    const int lr = t >> 2;   // 0..63 row for staging load
    const int lq = t & 3;    // 0..3  16B chunk
    float acc[4][4] = {};
    for (int k0 = 0; k0 < 256; k0 += 16) {
        float4 xv = *(const float4*)(x + (row0 + lr) * 256 + k0 + 4 * lq);
        float4 wv = *(const float4*)(w + (col0 + lr) * 256 + k0 + 4 * lq);
        xs[4*lq+0][lr] = xv.x; xs[4*lq+1][lr] = xv.y;
        xs[4*lq+2][lr] = xv.z; xs[4*lq+3][lr] = xv.w;
        wsd[4*lq+0][lr] = wv.x; wsd[4*lq+1][lr] = wv.y;
        wsd[4*lq+2][lr] = wv.z; wsd[4*lq+3][lr] = wv.w;
        __syncthreads();
#pragma unroll
        for (int kk = 0; kk < 16; ++kk) {
            float4 a  = *(const float4*)&xs[kk][4*ry];
            float4 bb = *(const float4*)&wsd[kk][4*cx];
            float av[4] = {a.x, a.y, a.z, a.w};
            float bv[4] = {bb.x, bb.y, bb.z, bb.w};
#pragma unroll
            for (int rr = 0; rr < 4; ++rr)
#pragma unroll
                for (int cc = 0; cc < 4; ++cc)
                    acc[rr][cc] = fmaf(av[rr], bv[cc], acc[rr][cc]);
        }
        __syncthreads();
    }
#pragma unroll
    for (int rr = 0; rr < 4; ++rr) {
        const int row = row0 + 4*ry + rr;
        const int b = row >> 9, l = row & 511;
#pragma unroll
        for (int cc = 0; cc < 4; ++cc) {
            const int o = col0 + 4*cx + cc;
            const int three = o >> 8;      // uniform per block (64-col tiles)
            const int hh = (o >> 5) & 7;
            const int dd = o & 31;
            int idx;
            if (three == 1)   // k -> transposed [b,h,d,l]
                idx = 262144 + ((b*8 + hh)*32 + dd)*512 + l;
            else              // q, v -> [b,h,l,d]
                idx = three * 262144 + ((b*8 + hh)*512 + l)*32 + dd;
            qkv_out[idx] = acc[rr][cc];
        }
    }
}

// ---------------------------------------------------------------------------
// K23 (fused rel + attention). One block per (b,i), 512 threads (8 waves).
//
// Phase 1 (rel): rel[h][j] = LN_h( gelu( rp[b,i,j,:] . w_rel[h,:] + b_rel[h] ) )
//   Wave w owns j in [64w, 64w+64), 2 j's per iter. Butterfly reduce:
//   xor1/xor2 run as DPP quad_perm adds (VALU pipe), only xor4/8/16 touch
//   the DS pipe (6 DS slots/iter vs 22 before) -- the DS pipe was co-critical
//   with the HBM stream.
//
// Phase 2 (attention): one wave per head. QK over K^T [B,H,D,L] (coalesced
//   dwordx4), rel added from LDS, softmax in-wave (DPP for xor1/2), p
//   overwrites rel row in-place, PV reads p via broadcast ds_read_b128.
// ---------------------------------------------------------------------------
__global__ __launch_bounds__(512) void k23_fused(const float* __restrict__ rp,
                                                 const float* __restrict__ wr,
                                                 const float* __restrict__ br,
                                                 const float* __restrict__ gam_p,
                                                 const float* __restrict__ bet_p,
                                                 const float* __restrict__ qg,
                                                 const float* __restrict__ kt,
                                                 const float* __restrict__ vg,
                                                 float* __restrict__ outg) {
    __shared__ float rel_lds[8 * 516];
    const int t    = threadIdx.x;
    const int lane = t & 63;
    const int wid  = t >> 6;              // 0..7
    const int b = blockIdx.x >> 9;
    const int i = blockIdx.x & 511;
    const int chunk = lane & 31;          // 8-float c-slice
    const int jh    = lane >> 5;          // which of 2 j's this iter
    const int h     = lane & 7;           // head owned after reduce

    // per-lane w_rel slice for all 8 heads (64 VGPRs)
    float wreg[8][8];
    {
        const float4* wr4 = (const float4*)wr;
#pragma unroll
        for (int hh = 0; hh < 8; ++hh) {
            float4 w0 = wr4[hh*64 + chunk*2];
            float4 w1 = wr4[hh*64 + chunk*2 + 1];
            wreg[hh][0]=w0.x; wreg[hh][1]=w0.y; wreg[hh][2]=w0.z; wreg[hh][3]=w0.w;
            wreg[hh][4]=w1.x; wreg[hh][5]=w1.y; wreg[hh][6]=w1.z; wreg[hh][7]=w1.w;
        }
    }
    const float brv = br[h], gmv = gam_p[h], btv = bet_p[h];

    const float* base = rp + ((long)(b*512 + i)*512 + (wid*64 + jh)) * 256
                           + chunk*8;
    float4 a0 = *(const float4*)(base);
    float4 a1 = *(const float4*)(base + 4);
#pragma unroll 2
    for (int it = 0; it < 32; ++it) {
        float4 n0 = a0, n1 = a1;
        if (it < 31) {                     // 1-deep prefetch of next j-pair
            const float* np = base + (2*(it+1))*256;
            n0 = *(const float4*)(np);
            n1 = *(const float4*)(np + 4);
        }
        float acc[8];
#pragma unroll
        for (int hh = 0; hh < 8; ++hh) {
            float s = 0.f;
            s = fmaf(a0.x, wreg[hh][0], s);
            s = fmaf(a0.y, wreg[hh][1], s);
            s = fmaf(a0.z, wreg[hh][2], s);
            s = fmaf(a0.w, wreg[hh][3], s);
            s = fmaf(a1.x, wreg[hh][4], s);
            s = fmaf(a1.y, wreg[hh][5], s);
            s = fmaf(a1.z, wreg[hh][6], s);
            s = fmaf(a1.w, wreg[hh][7], s);
            acc[hh] = s;
        }
        // interleaved butterfly + head-select; xor1/xor2 on VALU via DPP
#pragma unroll
        for (int hh = 0; hh < 8; ++hh) acc[hh] += dpp_xor1(acc[hh]);
        float v0 = (h & 1) ? acc[1] : acc[0];
        float v1 = (h & 1) ? acc[3] : acc[2];
        float v2 = (h & 1) ? acc[5] : acc[4];
        float v3 = (h & 1) ? acc[7] : acc[6];
        v0 += dpp_xor2(v0); v1 += dpp_xor2(v1);
        v2 += dpp_xor2(v2); v3 += dpp_xor2(v3);
        float u0 = (h & 2) ? v1 : v0;
        float u1 = (h & 2) ? v3 : v2;
        u0 += __shfl_xor(u0, 4); u1 += __shfl_xor(u1, 4);
        float tot = (h & 4) ? u1 : u0;
        tot += __shfl_xor(tot, 8);
        tot += __shfl_xor(tot, 16);

        const float r = tot + brv;
        const float g = 0.5f * r * (1.0f + erff(r * RSQRT2));
        // LayerNorm across the 8 heads of this octet (xor1/2 via DPP)
        float sg = g, sg2 = g * g;
        sg += dpp_xor1(sg); sg2 += dpp_xor1(sg2);
        sg += dpp_xor2(sg); sg2 += dpp_xor2(sg2);
        sg += __shfl_xor(sg, 4); sg2 += __shfl_xor(sg2, 4);
        const float mu  = sg * 0.125f;
        const float var = fmaf(sg2, 0.125f, -mu * mu);
        const float o = fmaf((g - mu) * rsqrtf(var + LN_EPS), gmv, btv);
        if ((lane & 31) < 8)               // one replica per (j,h) writes
            rel_lds[h * 516 + wid*64 + 2*it + jh] = o;
        a0 = n0; a1 = n1;
    }
    __syncthreads();

    // ---------------- Phase 2: attention, wave = head ----------------
    const int bh = b*8 + wid;
    const float* qp = qg + (bh*512 + i) * 32;
    float qs[32];
#pragma unroll
    for (int dd = 0; dd < 8; ++dd) {
        float4 q4 = *(const float4*)(qp + 4*dd);
        qs[4*dd+0]=q4.x; qs[4*dd+1]=q4.y; qs[4*dd+2]=q4.z; qs[4*dd+3]=q4.w;
    }
    const float4* kt4 = (const float4*)(kt + (long)bh * 32 * 512);
    float* relrow = &rel_lds[wid * 516];

    float4 s0 = {0.f,0.f,0.f,0.f}, s1 = {0.f,0.f,0.f,0.f};
#pragma unroll
    for (int dd = 0; dd < 32; ++dd) {
        float4 ka = kt4[dd*128 + lane];          // j = 4*lane..+3, coalesced
        float4 kb = kt4[dd*128 + 64 + lane];     // j = 256+4*lane..+3
        const float qd = qs[dd];
        s0.x = fmaf(qd, ka.x, s0.x); s0.y = fmaf(qd, ka.y, s0.y);
        s0.z = fmaf(qd, ka.z, s0.z); s0.w = fmaf(qd, ka.w, s0.w);
        s1.x = fmaf(qd, kb.x, s1.x); s1.y = fmaf(qd, kb.y, s1.y);
        s1.z = fmaf(qd, kb.z, s1.z); s1.w = fmaf(qd, kb.w, s1.w);
    }
    float4 r0 = *(const float4*)&relrow[4*lane];
    float4 r1 = *(const float4*)&relrow[256 + 4*lane];
    s0.x = (s0.x + r0.x) * SCALE; s0.y = (s0.y + r0.y) * SCALE;
    s0.z = (s0.z + r0.z) * SCALE; s0.w = (s0.w + r0.w) * SCALE;
    s1.x = (s1.x + r1.x) * SCALE; s1.y = (s1.y + r1.y) * SCALE;
    s1.z = (s1.z + r1.z) * SCALE; s1.w = (s1.w + r1.w) * SCALE;
    // row max (xor1/2 on VALU via DPP -- max order identical)
    float m = fmaxf(fmaxf(fmaxf(s0.x, s0.y), fmaxf(s0.z, s0.w)),
                    fmaxf(fmaxf(s1.x, s1.y), fmaxf(s1.z, s1.w)));
    m = fmaxf(m, dpp_xor1(m));
    m = fmaxf(m, dpp_xor2(m));
    m = fmaxf(m, __shfl_xor(m, 4));
    m = fmaxf(m, __shfl_xor(m, 8));
    m = fmaxf(m, __shfl_xor(m, 16));
    m = fmaxf(m, __shfl_xor(m, 32));
    // exp + sum
    s0.x = __expf(s0.x - m); s0.y = __expf(s0.y - m);
    s0.z = __expf(s0.z - m); s0.w = __expf(s0.w - m);
    s1.x = __expf(s1.x - m); s1.y = __expf(s1.y - m);
    s1.z = __expf(s1.z - m); s1.w = __expf(s1.w - m);
    float sum = ((s0.x + s0.y) + (s0.z + s0.w)) + ((s1.x + s1.y) + (s1.z + s1.w));
    sum += dpp_xor1(sum);
    sum += dpp_xor2(sum);
    sum += __shfl_xor(sum, 4);
    sum += __shfl_xor(sum, 8);
    sum += __shfl_xor(sum, 16);
    sum += __shfl_xor(sum, 32);
    const float inv = 1.0f / sum;
    s0.x *= inv; s0.y *= inv; s0.z *= inv; s0.w *= inv;
    s1.x *= inv; s1.y *= inv; s1.z *= inv; s1.w *= inv;
    // p overwrites rel row in place (wave-local, no barrier needed)
    *(float4*)&relrow[4*lane]       = s0;
    *(float4*)&relrow[256 + 4*lane] = s1;

    // PV: lane = (d = lane&31, half = lane>>5); p via broadcast ds_read_b128
    const int d = lane & 31;
    const int half = lane >> 5;
    const float* vp = vg + (long)bh * 512 * 32 + (half * 256) * 32 + d;
    const float* pw = relrow + half * 256;
    float a0s = 0.f, a1s = 0.f, a2s = 0.f, a3s = 0.f;
#pragma unroll 4
    for (int jj = 0; jj < 256; jj += 4) {
        float4 p4 = *(const float4*)&pw[jj];     // one b128, wave-broadcast
        a0s = fmaf(p4.x, vp[(jj + 0) * 32], a0s);
        a1s = fmaf(p4.y, vp[(jj + 1) * 32], a1s);
        a2s = fmaf(p4.z, vp[(jj + 2) * 32], a2s);
        a3s = fmaf(p4.w, vp[(jj + 3) * 32], a3s);
    }
    float acc = (a0s + a1s) + (a2s + a3s);
    acc += __shfl_xor(acc, 32);
    if (lane < 32)
        outg[(b*512 + i) * 256 + wid * 32 + d] = acc;
}

// ---------------------------------------------------------------------------
// K4: out = attn @ w_proj^T + b_proj.  M=1024, N=256, K=256.
// ---------------------------------------------------------------------------
__global__ __launch_bounds__(256) void k4_proj(const float* __restrict__ a_in,
                                               const float* __restrict__ w,
                                               const float* __restrict__ bp,
                                               float* __restrict__ outg) {
    __shared__ float xs[16][64];
    __shared__ float wsd[16][64];
    const int row0 = blockIdx.x * 64;
    const int col0 = blockIdx.y * 64;
    const int t  = threadIdx.x;
    const int ry = t >> 4;
    const int cx = t & 15;
    const int lr = t >> 2;
    const int lq = t & 3;
    float acc[4][4] = {};
    for (int k0 = 0; k0 < 256; k0 += 16) {
        float4 xv = *(const float4*)(a_in + (row0 + lr) * 256 + k0 + 4 * lq);
        float4 wv = *(const float4*)(w + (col0 + lr) * 256 + k0 + 4 * lq);
        xs[4*lq+0][lr] = xv.x; xs[4*lq+1][lr] = xv.y;
        xs[4*lq+2][lr] = xv.z; xs[4*lq+3][lr] = xv.w;
        wsd[4*lq+0][lr] = wv.x; wsd[4*lq+1][lr] = wv.y;
        wsd[4*lq+2][lr] = wv.z; wsd[4*lq+3][lr] = wv.w;
        __syncthreads();
#pragma unroll
        for (int kk = 0; kk < 16; ++kk) {
            float4 a  = *(const float4*)&xs[kk][4*ry];
            float4 bb = *(const float4*)&wsd[kk][4*cx];
            float av[4] = {a.x, a.y, a.z, a.w};
            float bv[4] = {bb.x, bb.y, bb.z, bb.w};
#pragma unroll
            for (int rr = 0; rr < 4; ++rr)
#pragma unroll
                for (int cc = 0; cc < 4; ++cc)
                    acc[rr][cc] = fmaf(av[rr], bv[cc], acc[rr][cc]);
        }
        __syncthreads();
    }
#pragma unroll
    for (int rr = 0; rr < 4; ++rr) {
        const int row = row0 + 4*ry + rr;
#pragma unroll
        for (int cc = 0; cc < 4; ++cc) {
            const int col = col0 + 4*cx + cc;
            outg[row * 256 + col] = acc[rr][cc] + bp[col];
        }
    }
}

// ---------------------------------------------------------------------------
extern "C" void kernel_launch(void* const* d_in, const int* in_sizes, int n_in,
                              void* d_out, int out_size, void* d_ws, size_t ws_size,
                              hipStream_t stream) {
    const float* x      = (const float*)d_in[0];
    const float* rp     = (const float*)d_in[1];
    const float* w_qkv  = (const float*)d_in[2];
    const float* w_rel  = (const float*)d_in[3];
    const float* b_rel  = (const float*)d_in[4];
    const float* gamma  = (const float*)d_in[5];
    const float* beta   = (const float*)d_in[6];
    const float* w_proj = (const float*)d_in[7];
    const float* b_proj = (const float*)d_in[8];
    float* out = (float*)d_out;
    float* ws  = (float*)d_ws;

    // workspace layout (floats):
    // q: [0, 262144)   k_t [B,H,D,L]: [262144, 524288)   v: [524288, 786432)
    // attn [B,L,C]: [786432, 1048576)   (rel never touches HBM)
    float* q    = ws;
    float* kk   = ws + 262144;
    float* vv   = ws + 524288;
    float* attn = ws + 786432;

    k1_qkv<<<dim3(16, 12), 256, 0, stream>>>(x, w_qkv, q);
    k23_fused<<<1024, 512, 0, stream>>>(rp, w_rel, b_rel, gamma, beta,
                                        q, kk, vv, attn);
    k4_proj<<<dim3(16, 4), 256, 0, stream>>>(attn, w_proj, b_proj, out);
}